// Round 4
// baseline (625.867 us; speedup 1.0000x reference)
//
#include <hip/hip_runtime.h>

#define DEV __device__ __forceinline__

using f16x8 = _Float16 __attribute__((ext_vector_type(8)));
using f16x4 = _Float16 __attribute__((ext_vector_type(4)));
using f32x4 = float __attribute__((ext_vector_type(4)));

DEV f32x4 mfma16(f16x8 a, f16x8 b, f32x4 c) {
    return __builtin_amdgcn_mfma_f32_16x16x32_f16(a, b, c, 0, 0, 0);
}

DEV void gload16(const void* g, void* l) {
    __builtin_amdgcn_global_load_lds(
        (const __attribute__((address_space(1))) void*)g,
        (__attribute__((address_space(3))) void*)l, 16, 0, 0);
}

// ---------------------------------------------------------------------------
// GEMM: C[M,N] = A[M,K] (f16 row-major) * Bt[N,K]^T (f16, N-major "BT" layout)
// 128x128 tile, BK=64, 4 waves (2x2), mfma_f32_16x16x32_f16, XOR-swizzled LDS.
// XCD-aware bijective block swizzle (T1, m157 form; all grids %8==0).
// MODE 0: QKV scatter epilogue  (o0=q [bh][s][dk], o1=k [bh][s][dk], o2=vT [bh][dv][s])
// MODE 1: resid1 = acc + x      (ep0 = x fp32, o0 = fp32)
// MODE 2: ff1 = relu(acc + b1)  (ep0 = b1,     o0 = f16)
// MODE 3: resid2 = acc + b2 + h1f (ep0 = b2, ep1 = h1f, o0 = fp32)
// ---------------------------------------------------------------------------
template <int MODE>
__global__ __launch_bounds__(256, 2) void gemm_bt(
    const _Float16* __restrict__ A, const _Float16* __restrict__ Bt,
    int M, int N, int K,
    const float* __restrict__ ep0, const float* __restrict__ ep1,
    void* __restrict__ o0, void* __restrict__ o1, void* __restrict__ o2)
{
    __shared__ __align__(16) _Float16 As[128 * 64];
    __shared__ __align__(16) _Float16 Bs[128 * 64];
    const int tid  = threadIdx.x;
    const int wave = tid >> 6, lane = tid & 63;
    const int l16  = lane & 15, g = lane >> 4;
    // T1: XCD-aware swizzle. Linear id round-robins over 8 XCDs; remap so each
    // XCD gets a contiguous chunk of tiles (nwg % 8 == 0 for all our grids).
    const int nwg   = gridDim.x * gridDim.y;
    const int lid   = blockIdx.x + gridDim.x * blockIdx.y;
    const int chunk = nwg >> 3;
    const int wgid  = (lid & 7) * chunk + (lid >> 3);
    const int bx = wgid % gridDim.x, by = wgid / gridDim.x;
    const int m0 = bx * 128, n0 = by * 128;
    const int wm = (wave >> 1) * 64, wn = (wave & 1) * 64;

    f32x4 acc[4][4] = {};

    for (int kt = 0; kt < K; kt += 64) {
#pragma unroll
        for (int it = 0; it < 4; ++it) {  // stage A tile (16 KB)
            const int off  = it * 4096 + tid * 16;
            const int row  = off >> 7;
            const int colb = (off & 127) ^ ((row & 7) << 4);  // inverse swizzle on source
            gload16(A + (size_t)(m0 + row) * K + kt + (colb >> 1), (char*)As + off);
        }
#pragma unroll
        for (int it = 0; it < 4; ++it) {  // stage B tile
            const int off  = it * 4096 + tid * 16;
            const int row  = off >> 7;
            const int colb = (off & 127) ^ ((row & 7) << 4);
            gload16(Bt + (size_t)(n0 + row) * K + kt + (colb >> 1), (char*)Bs + off);
        }
        __syncthreads();  // vmcnt(0) drain + barrier
#pragma unroll
        for (int kk = 0; kk < 2; ++kk) {
            f16x8 af[4], bfv[4];
#pragma unroll
            for (int i = 0; i < 4; ++i) {
                const int ar = wm + i * 16 + l16;
                const int cb = ((kk * 32 + g * 8) << 1) ^ ((ar & 7) << 4);
                af[i] = *(const f16x8*)((const char*)As + (ar << 7) + cb);
            }
#pragma unroll
            for (int j = 0; j < 4; ++j) {
                const int br = wn + j * 16 + l16;
                const int cb = ((kk * 32 + g * 8) << 1) ^ ((br & 7) << 4);
                bfv[j] = *(const f16x8*)((const char*)Bs + (br << 7) + cb);
            }
#pragma unroll
            for (int i = 0; i < 4; ++i)
#pragma unroll
                for (int j = 0; j < 4; ++j)
                    acc[i][j] = mfma16(af[i], bfv[j], acc[i][j]);
        }
        __syncthreads();
    }

#pragma unroll
    for (int i = 0; i < 4; ++i) {
#pragma unroll
        for (int j = 0; j < 4; ++j) {
#pragma unroll
            for (int r = 0; r < 4; ++r) {
                const int m = m0 + wm + i * 16 + g * 4 + r;   // D row = (lane>>4)*4+reg
                const int n = n0 + wn + j * 16 + l16;          // D col = lane&15
                const float val = acc[i][j][r];
                if constexpr (MODE == 0) {
                    const int b = m >> 11, s = m & 2047;
                    const int which = n >> 10, hh = (n >> 6) & 15, dd = n & 63;
                    const size_t bh = (size_t)(b * 16 + hh);
                    const _Float16 hv = (_Float16)val;
                    if (which == 0)      ((_Float16*)o0)[(bh * 2048 + s) * 64 + dd] = hv;
                    else if (which == 1) ((_Float16*)o1)[(bh * 2048 + s) * 64 + dd] = hv;
                    else                 ((_Float16*)o2)[(bh * 64 + dd) * 2048 + s] = hv;
                } else if constexpr (MODE == 1) {
                    const size_t idx = (size_t)m * N + n;
                    ((float*)o0)[idx] = val + ep0[idx];
                } else if constexpr (MODE == 2) {
                    float v = val + ep0[n];
                    ((_Float16*)o0)[(size_t)m * N + n] = (_Float16)(v > 0.f ? v : 0.f);
                } else {
                    const size_t idx = (size_t)m * N + n;
                    ((float*)o0)[idx] = val + ep0[n] + ep1[idx];
                }
            }
        }
    }
}

// ---------------------------------------------------------------------------
// Flash attention, causal. Block = 4 waves; wave w owns two 16-row q tiles
// paired for load balance: tA = bx*4+w (0..63) and 127-tA -> uniform waves.
// Structure identical to the verified R2 kernel; only V loads are hoisted to
// the top of the iteration (latency hidden under QK^T+softmax) and MFMA
// clusters are wrapped in s_setprio (T5).
// ---------------------------------------------------------------------------
__global__ __launch_bounds__(256, 4) void attn_kernel(
    const _Float16* __restrict__ Q, const _Float16* __restrict__ Kb,
    const _Float16* __restrict__ Vt, _Float16* __restrict__ ctx)
{
    __shared__ __align__(16) _Float16 P_lds[4][16][72];
    __shared__ __align__(16) float f_lds[4][16];
    const int tid = threadIdx.x;
    const int w = tid >> 6, lane = tid & 63;
    const int l16 = lane & 15, g = lane >> 4;
    const int bh = blockIdx.y;
    const int b = bh >> 4, h = bh & 15;
    const int tA = blockIdx.x * 4 + w;      // 0..63

    for (int half = 0; half < 2; ++half) {
        const int t = half ? (127 - tA) : tA;
        const int qbase = t * 16;
        const int qg = qbase + l16;

        const _Float16* qrow = Q + ((size_t)bh * 2048 + qg) * 64;
        const f16x8 qf0 = *(const f16x8*)(qrow + g * 8);
        const f16x8 qf1 = *(const f16x8*)(qrow + 32 + g * 8);

        f32x4 cacc[4] = {};
        float m_run = -INFINITY, l_run = 0.f;
        const int limit = qbase + 16;

        for (int kb0 = 0; kb0 < limit; kb0 += 64) {
            // ---- V prefetch (consumed only after softmax, ~500 cy later) ----
            f16x8 vf[4][2];
            const _Float16* vbase = Vt + ((size_t)bh * 64 + l16) * 2048 + kb0;
#pragma unroll
            for (int jt = 0; jt < 4; ++jt) {
                vf[jt][0] = *(const f16x8*)(vbase + jt * 16 * 2048 + g * 8);
                vf[jt][1] = *(const f16x8*)(vbase + jt * 16 * 2048 + 32 + g * 8);
            }
            // ---- QK^T over 64 keys (4 groups of 16) ----
            f32x4 st[4] = {{0.f,0.f,0.f,0.f},{0.f,0.f,0.f,0.f},
                           {0.f,0.f,0.f,0.f},{0.f,0.f,0.f,0.f}};
            const _Float16* kbase = Kb + ((size_t)bh * 2048 + kb0 + l16) * 64;
            __builtin_amdgcn_s_setprio(1);
#pragma unroll
            for (int s = 0; s < 4; ++s) {
                const _Float16* krow = kbase + s * (16 * 64);
                st[s] = mfma16(*(const f16x8*)(krow + g * 8),      qf0, st[s]);
                st[s] = mfma16(*(const f16x8*)(krow + 32 + g * 8), qf1, st[s]);
            }
            __builtin_amdgcn_s_setprio(0);
            // ---- online softmax (lane holds 16 scores for q=l16) ----
            float sv[16];
            float tmax = -INFINITY;
#pragma unroll
            for (int s = 0; s < 4; ++s)
#pragma unroll
                for (int r = 0; r < 4; ++r) {
                    const int kg = kb0 + s * 16 + g * 4 + r;
                    float v = st[s][r] * 0.03125f;   // 1/sqrt(1024)
                    v = (kg <= qg) ? v : -INFINITY;
                    sv[s * 4 + r] = v;
                    tmax = fmaxf(tmax, v);
                }
            tmax = fmaxf(tmax, __shfl_xor(tmax, 16));
            tmax = fmaxf(tmax, __shfl_xor(tmax, 32));
            const float m_new = fmaxf(m_run, tmax);
            const float alpha = __expf(m_run - m_new);
            float tsum = 0.f;
            f16x4 p[4];
#pragma unroll
            for (int s = 0; s < 4; ++s)
#pragma unroll
                for (int r = 0; r < 4; ++r) {
                    const float e = __expf(sv[s * 4 + r] - m_new);
                    tsum += e;
                    p[s][r] = (_Float16)e;
                }
            tsum += __shfl_xor(tsum, 16);
            tsum += __shfl_xor(tsum, 32);
            l_run = l_run * alpha + tsum;
            m_run = m_new;

            // P^T frag (keys 16s+4g..+3 for column q=l16) -> P_lds[q][key]
#pragma unroll
            for (int s = 0; s < 4; ++s)
                *(f16x4*)&P_lds[w][l16][s * 16 + g * 4] = p[s];
            if (g == 0) f_lds[w][l16] = alpha;   // broadcast alpha per q-row

            // wave-private LDS: DS pipe is in-order per wave, no barrier needed
            const f32x4 al  = *(const f32x4*)&f_lds[w][g * 4];
            const f16x8 pf0 = *(const f16x8*)&P_lds[w][l16][g * 8];       // keys 0..31
            const f16x8 pf1 = *(const f16x8*)&P_lds[w][l16][32 + g * 8];  // keys 32..63
            __builtin_amdgcn_s_setprio(1);
#pragma unroll
            for (int jt = 0; jt < 4; ++jt) {
#pragma unroll
                for (int r = 0; r < 4; ++r) cacc[jt][r] *= al[r];
                cacc[jt] = mfma16(pf0, vf[jt][0], cacc[jt]);
                cacc[jt] = mfma16(pf1, vf[jt][1], cacc[jt]);
            }
            __builtin_amdgcn_s_setprio(0);
        }

        if (g == 0) f_lds[w][l16] = 1.f / l_run;
        const f32x4 il = *(const f32x4*)&f_lds[w][g * 4];
#pragma unroll
        for (int jt = 0; jt < 4; ++jt)
#pragma unroll
            for (int r = 0; r < 4; ++r)
                ctx[((size_t)b * 2048 + qbase + g * 4 + r) * 1024 + h * 64 + jt * 16 + l16]
                    = (_Float16)(cacc[jt][r] * il[r]);
    }
}

// ---------------------------------------------------------------------------
// LayerNorm over rows of 1024 fp32; optional fp32 and f16 outputs.
// ---------------------------------------------------------------------------
__global__ __launch_bounds__(256) void ln_kernel(
    const float* __restrict__ in, const float* __restrict__ gam, const float* __restrict__ bet,
    float* __restrict__ out32, _Float16* __restrict__ out16)
{
    const int row = blockIdx.x, tid = threadIdx.x;
    const float4 x = ((const float4*)(in + (size_t)row * 1024))[tid];
    float s  = x.x + x.y + x.z + x.w;
    float s2 = x.x * x.x + x.y * x.y + x.z * x.z + x.w * x.w;
#pragma unroll
    for (int o = 32; o > 0; o >>= 1) {
        s  += __shfl_xor(s, o);
        s2 += __shfl_xor(s2, o);
    }
    __shared__ float red[8];
    if ((tid & 63) == 0) { red[tid >> 6] = s; red[4 + (tid >> 6)] = s2; }
    __syncthreads();
    const float S  = red[0] + red[1] + red[2] + red[3];
    const float S2 = red[4] + red[5] + red[6] + red[7];
    const float mu = S * (1.f / 1024.f);
    const float ir = rsqrtf(S2 * (1.f / 1024.f) - mu * mu + 1e-5f);
    const float4 gv = ((const float4*)gam)[tid];
    const float4 bv = ((const float4*)bet)[tid];
    float4 o;
    o.x = (x.x - mu) * ir * gv.x + bv.x;
    o.y = (x.y - mu) * ir * gv.y + bv.y;
    o.z = (x.z - mu) * ir * gv.z + bv.z;
    o.w = (x.w - mu) * ir * gv.w + bv.w;
    if (out32) ((float4*)(out32 + (size_t)row * 1024))[tid] = o;
    if (out16) {
        f16x4 h;
        h[0] = (_Float16)o.x; h[1] = (_Float16)o.y; h[2] = (_Float16)o.z; h[3] = (_Float16)o.w;
        *(f16x4*)(out16 + (size_t)row * 1024 + tid * 4) = h;
    }
}

// fp32 -> fp16 elementwise (float4 granularity)
__global__ __launch_bounds__(256) void cast_f16(const float* __restrict__ in,
                                                _Float16* __restrict__ out, int n4)
{
    const int i = blockIdx.x * 256 + threadIdx.x;
    if (i < n4) {
        const float4 v = ((const float4*)in)[i];
        f16x4 h;
        h[0] = (_Float16)v.x; h[1] = (_Float16)v.y; h[2] = (_Float16)v.z; h[3] = (_Float16)v.w;
        ((f16x4*)out)[i] = h;
    }
}

// dst[n][k] = (f16) src[k][n] — LDS-tiled transpose, K,N multiples of 64
__global__ __launch_bounds__(256) void transpose_cast(const float* __restrict__ src,
                                                      _Float16* __restrict__ dst, int K, int N)
{
    __shared__ float tile[64][65];
    const int n0 = blockIdx.x * 64, k0 = blockIdx.y * 64;
    const int tid = threadIdx.x;
#pragma unroll
    for (int it = 0; it < 16; ++it) {
        const int idx = it * 256 + tid;
        const int r = idx >> 6, c = idx & 63;
        tile[r][c] = src[(size_t)(k0 + r) * N + n0 + c];
    }
    __syncthreads();
#pragma unroll
    for (int it = 0; it < 16; ++it) {
        const int idx = it * 256 + tid;
        const int r = idx >> 6, c = idx & 63;
        dst[(size_t)(n0 + r) * K + k0 + c] = (_Float16)tile[c][r];
    }
}

// Wqkv_bt[n][d] = W{q|k|v}[h][d][kk]  (n = which*1024 + h*64 + kk)
__global__ __launch_bounds__(256) void pack_qkv_w(const float* __restrict__ Wq,
                                                  const float* __restrict__ Wk,
                                                  const float* __restrict__ Wv,
                                                  _Float16* __restrict__ dst)
{
    __shared__ float tile[64][65];
    const int n0 = blockIdx.x * 64, d0 = blockIdx.y * 64;
    const int which = n0 >> 10, hh = (n0 >> 6) & 15;
    const float* W = which == 0 ? Wq : (which == 1 ? Wk : Wv);
    const int tid = threadIdx.x;
#pragma unroll
    for (int it = 0; it < 16; ++it) {
        const int idx = it * 256 + tid;
        const int r = idx >> 6, c = idx & 63;      // r = d offset, c = kk
        tile[r][c] = W[((size_t)hh * 1024 + d0 + r) * 64 + c];
    }
    __syncthreads();
#pragma unroll
    for (int it = 0; it < 16; ++it) {
        const int idx = it * 256 + tid;
        const int r = idx >> 6, c = idx & 63;      // r = kk (n offset), c = d offset
        dst[(size_t)(n0 + r) * 1024 + d0 + c] = (_Float16)tile[c][r];
    }
}

extern "C" void kernel_launch(void* const* d_in, const int* in_sizes, int n_in,
                              void* d_out, int out_size, void* d_ws, size_t ws_size,
                              hipStream_t stream)
{
    const float* x    = (const float*)d_in[0];
    const float* Wq   = (const float*)d_in[1];
    const float* Wk   = (const float*)d_in[2];
    const float* Wv   = (const float*)d_in[3];
    const float* Wo   = (const float*)d_in[4];
    const float* ln1g = (const float*)d_in[5];
    const float* ln1b = (const float*)d_in[6];
    const float* W1   = (const float*)d_in[7];
    const float* b1   = (const float*)d_in[8];
    const float* W2   = (const float*)d_in[9];
    const float* b2   = (const float*)d_in[10];
    const float* ln2g = (const float*)d_in[11];
    const float* ln2b = (const float*)d_in[12];
    float* out = (float*)d_out;

    char* ws = (char*)d_ws;
    size_t off = 0;
    auto alloc = [&](size_t bytes) {
        void* p = ws + off;
        off += (bytes + 255) & ~(size_t)255;
        return p;
    };
    _Float16* x_h   = (_Float16*)alloc(8192ULL * 1024 * 2);
    _Float16* wqkv  = (_Float16*)alloc(3072ULL * 1024 * 2);
    _Float16* wo_t  = (_Float16*)alloc(1024ULL * 1024 * 2);
    _Float16* w1_t  = (_Float16*)alloc(4096ULL * 1024 * 2);
    _Float16* w2_t  = (_Float16*)alloc(1024ULL * 4096 * 2);
    _Float16* qbuf  = (_Float16*)alloc(8192ULL * 1024 * 2);  // region A: q,k,vT,ctx
    _Float16* kbuf  = (_Float16*)alloc(8192ULL * 1024 * 2);
    _Float16* vt    = (_Float16*)alloc(8192ULL * 1024 * 2);
    _Float16* ctx   = (_Float16*)alloc(8192ULL * 1024 * 2);
    _Float16* ff1   = qbuf;  // reuse region A (67.1 MB) after attention+Wo
    float*    resid = (float*)alloc(8192ULL * 1024 * 4);     // resid1, then resid2
    float*    h1f   = (float*)alloc(8192ULL * 1024 * 4);
    _Float16* h1h   = (_Float16*)alloc(8192ULL * 1024 * 2);
    if (off > ws_size) return;  // insufficient workspace -> fail loudly

    // weight/activation packing
    cast_f16<<<8192, 256, 0, stream>>>(x, x_h, 2097152);
    pack_qkv_w<<<dim3(48, 16), 256, 0, stream>>>(Wq, Wk, Wv, wqkv);
    transpose_cast<<<dim3(16, 16), 256, 0, stream>>>(Wo, wo_t, 1024, 1024);
    transpose_cast<<<dim3(64, 16), 256, 0, stream>>>(W1, w1_t, 1024, 4096);
    transpose_cast<<<dim3(16, 64), 256, 0, stream>>>(W2, w2_t, 4096, 1024);

    // QKV projection (fused, scattered epilogue)
    gemm_bt<0><<<dim3(64, 24), 256, 0, stream>>>(x_h, wqkv, 8192, 3072, 1024,
                                                 nullptr, nullptr, qbuf, kbuf, vt);
    // causal flash attention (paired q-tiles, V prefetch, setprio)
    attn_kernel<<<dim3(16, 64), 256, 0, stream>>>(qbuf, kbuf, vt, ctx);
    // output projection + residual
    gemm_bt<1><<<dim3(64, 8), 256, 0, stream>>>(ctx, wo_t, 8192, 1024, 1024,
                                                x, nullptr, resid, nullptr, nullptr);
    ln_kernel<<<8192, 256, 0, stream>>>(resid, ln1g, ln1b, h1f, h1h);
    // FFN
    gemm_bt<2><<<dim3(64, 32), 256, 0, stream>>>(h1h, w1_t, 8192, 4096, 1024,
                                                 b1, nullptr, ff1, nullptr, nullptr);
    gemm_bt<3><<<dim3(64, 8), 256, 0, stream>>>(ff1, w2_t, 8192, 1024, 4096,
                                                b2, h1f, resid, nullptr, nullptr);
    ln_kernel<<<8192, 256, 0, stream>>>(resid, ln2g, ln2b, out, nullptr);
}

// Round 5
// 387.054 us; speedup vs baseline: 1.6170x; 1.6170x over previous
//
#include <hip/hip_runtime.h>

#define DEV __device__ __forceinline__

using f16x8 = _Float16 __attribute__((ext_vector_type(8)));
using f16x4 = _Float16 __attribute__((ext_vector_type(4)));
using f32x4 = float __attribute__((ext_vector_type(4)));

DEV f32x4 mfma16(f16x8 a, f16x8 b, f32x4 c) {
    return __builtin_amdgcn_mfma_f32_16x16x32_f16(a, b, c, 0, 0, 0);
}

DEV void gload16(const void* g, void* l) {
    __builtin_amdgcn_global_load_lds(
        (const __attribute__((address_space(1))) void*)g,
        (__attribute__((address_space(3))) void*)l, 16, 0, 0);
}

// ---------------------------------------------------------------------------
// GEMM: C[M,N] = A[M,K] (f16 row-major) * Bt[N,K]^T (f16, N-major "BT" layout)
// 128x128 tile, BK=64, 4 waves (2x2), mfma_f32_16x16x32_f16, XOR-swizzled LDS.
// (R2-exact: default block mapping — T1 chunk-swizzle regressed these tall
//  grids by destroying A-slice locality per XCD.)
// MODE 0: QKV scatter epilogue  (o0=q [bh][s][dk], o1=k [bh][s][dk], o2=vT [bh][dv][s])
// MODE 1: resid1 = acc + x      (ep0 = x fp32, o0 = fp32)
// MODE 2: ff1 = relu(acc + b1)  (ep0 = b1,     o0 = f16)
// MODE 3: resid2 = acc + b2 + h1f (ep0 = b2, ep1 = h1f, o0 = fp32)
// ---------------------------------------------------------------------------
template <int MODE>
__global__ __launch_bounds__(256, 2) void gemm_bt(
    const _Float16* __restrict__ A, const _Float16* __restrict__ Bt,
    int M, int N, int K,
    const float* __restrict__ ep0, const float* __restrict__ ep1,
    void* __restrict__ o0, void* __restrict__ o1, void* __restrict__ o2)
{
    __shared__ __align__(16) _Float16 As[128 * 64];
    __shared__ __align__(16) _Float16 Bs[128 * 64];
    const int tid  = threadIdx.x;
    const int wave = tid >> 6, lane = tid & 63;
    const int l16  = lane & 15, g = lane >> 4;
    const int m0 = blockIdx.x * 128, n0 = blockIdx.y * 128;
    const int wm = (wave >> 1) * 64, wn = (wave & 1) * 64;

    f32x4 acc[4][4] = {};

    for (int kt = 0; kt < K; kt += 64) {
#pragma unroll
        for (int it = 0; it < 4; ++it) {  // stage A tile (16 KB)
            const int off  = it * 4096 + tid * 16;
            const int row  = off >> 7;
            const int colb = (off & 127) ^ ((row & 7) << 4);  // inverse swizzle on source
            gload16(A + (size_t)(m0 + row) * K + kt + (colb >> 1), (char*)As + off);
        }
#pragma unroll
        for (int it = 0; it < 4; ++it) {  // stage B tile
            const int off  = it * 4096 + tid * 16;
            const int row  = off >> 7;
            const int colb = (off & 127) ^ ((row & 7) << 4);
            gload16(Bt + (size_t)(n0 + row) * K + kt + (colb >> 1), (char*)Bs + off);
        }
        __syncthreads();  // vmcnt(0) drain + barrier
#pragma unroll
        for (int kk = 0; kk < 2; ++kk) {
            f16x8 af[4], bfv[4];
#pragma unroll
            for (int i = 0; i < 4; ++i) {
                const int ar = wm + i * 16 + l16;
                const int cb = ((kk * 32 + g * 8) << 1) ^ ((ar & 7) << 4);
                af[i] = *(const f16x8*)((const char*)As + (ar << 7) + cb);
            }
#pragma unroll
            for (int j = 0; j < 4; ++j) {
                const int br = wn + j * 16 + l16;
                const int cb = ((kk * 32 + g * 8) << 1) ^ ((br & 7) << 4);
                bfv[j] = *(const f16x8*)((const char*)Bs + (br << 7) + cb);
            }
#pragma unroll
            for (int i = 0; i < 4; ++i)
#pragma unroll
                for (int j = 0; j < 4; ++j)
                    acc[i][j] = mfma16(af[i], bfv[j], acc[i][j]);
        }
        __syncthreads();
    }

#pragma unroll
    for (int i = 0; i < 4; ++i) {
#pragma unroll
        for (int j = 0; j < 4; ++j) {
#pragma unroll
            for (int r = 0; r < 4; ++r) {
                const int m = m0 + wm + i * 16 + g * 4 + r;   // D row = (lane>>4)*4+reg
                const int n = n0 + wn + j * 16 + l16;          // D col = lane&15
                const float val = acc[i][j][r];
                if constexpr (MODE == 0) {
                    const int b = m >> 11, s = m & 2047;
                    const int which = n >> 10, hh = (n >> 6) & 15, dd = n & 63;
                    const size_t bh = (size_t)(b * 16 + hh);
                    const _Float16 hv = (_Float16)val;
                    if (which == 0)      ((_Float16*)o0)[(bh * 2048 + s) * 64 + dd] = hv;
                    else if (which == 1) ((_Float16*)o1)[(bh * 2048 + s) * 64 + dd] = hv;
                    else                 ((_Float16*)o2)[(bh * 64 + dd) * 2048 + s] = hv;
                } else if constexpr (MODE == 1) {
                    const size_t idx = (size_t)m * N + n;
                    ((float*)o0)[idx] = val + ep0[idx];
                } else if constexpr (MODE == 2) {
                    float v = val + ep0[n];
                    ((_Float16*)o0)[(size_t)m * N + n] = (_Float16)(v > 0.f ? v : 0.f);
                } else {
                    const size_t idx = (size_t)m * N + n;
                    ((float*)o0)[idx] = val + ep0[n] + ep1[idx];
                }
            }
        }
    }
}

// ---------------------------------------------------------------------------
// Flash attention, causal, block-cooperative KV staging.
// Block = 4 waves = one 64-row q-block; wave w owns rows 64T+16w..+15.
// Pairing T <-> 31-T balances blocks (33 KV-64 tiles each). Per tile, K
// ([key][d]) and V ([dv][key]) are staged to LDS by all 256 threads via
// global_load_lds with XOR-swizzled source (read-side <=2-way banks), then
// each wave computes QK^T -> online softmax -> PV from LDS. Mask applied only
// on the diagonal tile (kt==T). Softmax/P_lds/f_lds identical to verified R2.
// ---------------------------------------------------------------------------
__global__ __launch_bounds__(256, 4) void attn_kernel(
    const _Float16* __restrict__ Q, const _Float16* __restrict__ Kb,
    const _Float16* __restrict__ Vt, _Float16* __restrict__ ctx)
{
    __shared__ __align__(16) _Float16 Ks[64 * 64];        // [key][d], swizzled
    __shared__ __align__(16) _Float16 Vs[64 * 64];        // [dv][key], swizzled
    __shared__ __align__(16) _Float16 P_lds[4][16][72];
    __shared__ __align__(16) float f_lds[4][16];
    const int tid = threadIdx.x;
    const int w = tid >> 6, lane = tid & 63;
    const int l16 = lane & 15, g = lane >> 4;
    const int bh = blockIdx.y;
    const int b = bh >> 4, h = bh & 15;
    const int tA = blockIdx.x;              // 0..15

    const _Float16* Kh = Kb + (size_t)bh * 2048 * 64;
    const _Float16* Vh = Vt + (size_t)bh * 64 * 2048;
    const int swl = (l16 & 7) << 4;

    for (int half = 0; half < 2; ++half) {
        const int T = half ? (31 - tA) : tA;        // q-block index, 0..31
        const int qbase = T * 64 + w * 16;
        const int qg = qbase + l16;

        const _Float16* qrow = Q + ((size_t)bh * 2048 + qg) * 64;
        const f16x8 qf0 = *(const f16x8*)(qrow + g * 8);
        const f16x8 qf1 = *(const f16x8*)(qrow + 32 + g * 8);

        f32x4 cacc[4] = {};
        float m_run = -INFINITY, l_run = 0.f;

        for (int kt = 0; kt <= T; ++kt) {
            const int kb0 = kt * 64;
            // ---- stage K,V 64-key tile (8 KB each) ----
#pragma unroll
            for (int it = 0; it < 2; ++it) {
                const int off  = it * 4096 + tid * 16;
                const int row  = off >> 7;
                const int colb = (off & 127) ^ ((row & 7) << 4);
                gload16(Kh + (size_t)(kb0 + row) * 64 + (colb >> 1), (char*)Ks + off);
            }
#pragma unroll
            for (int it = 0; it < 2; ++it) {
                const int off  = it * 4096 + tid * 16;
                const int row  = off >> 7;
                const int colb = (off & 127) ^ ((row & 7) << 4);
                gload16(Vh + (size_t)row * 2048 + kb0 + (colb >> 1), (char*)Vs + off);
            }
            __syncthreads();   // vmcnt(0) drain + barrier

            // ---- QK^T over 64 keys from LDS ----
            f32x4 st[4] = {{0.f,0.f,0.f,0.f},{0.f,0.f,0.f,0.f},
                           {0.f,0.f,0.f,0.f},{0.f,0.f,0.f,0.f}};
            __builtin_amdgcn_s_setprio(1);
#pragma unroll
            for (int s = 0; s < 4; ++s) {
                const char* kr = (const char*)Ks + (16 * s + l16) * 128;
                const f16x8 klo = *(const f16x8*)(kr + ((g * 16) ^ swl));
                const f16x8 khi = *(const f16x8*)(kr + ((64 + g * 16) ^ swl));
                st[s] = mfma16(klo, qf0, st[s]);
                st[s] = mfma16(khi, qf1, st[s]);
            }
            __builtin_amdgcn_s_setprio(0);

            // ---- online softmax (lane holds 16 scores for q=l16) ----
            const bool maskt = (kt == T);   // only diagonal tile needs masking
            float sv[16];
            float tmax = -INFINITY;
#pragma unroll
            for (int s = 0; s < 4; ++s)
#pragma unroll
                for (int r = 0; r < 4; ++r) {
                    const int kg = kb0 + s * 16 + g * 4 + r;
                    float v = st[s][r] * 0.03125f;   // 1/sqrt(1024)
                    v = (!maskt || kg <= qg) ? v : -INFINITY;
                    sv[s * 4 + r] = v;
                    tmax = fmaxf(tmax, v);
                }
            tmax = fmaxf(tmax, __shfl_xor(tmax, 16));
            tmax = fmaxf(tmax, __shfl_xor(tmax, 32));
            const float m_new = fmaxf(m_run, tmax);
            const float alpha = __expf(m_run - m_new);
            float tsum = 0.f;
            f16x4 p[4];
#pragma unroll
            for (int s = 0; s < 4; ++s)
#pragma unroll
                for (int r = 0; r < 4; ++r) {
                    const float e = __expf(sv[s * 4 + r] - m_new);
                    tsum += e;
                    p[s][r] = (_Float16)e;
                }
            tsum += __shfl_xor(tsum, 16);
            tsum += __shfl_xor(tsum, 32);
            l_run = l_run * alpha + tsum;
            m_run = m_new;

            // P^T frag (keys 16s+4g..+3 for column q=l16) -> P_lds[q][key]
#pragma unroll
            for (int s = 0; s < 4; ++s)
                *(f16x4*)&P_lds[w][l16][s * 16 + g * 4] = p[s];
            if (g == 0) f_lds[w][l16] = alpha;   // broadcast alpha per q-row

            // wave-private LDS: DS pipe is in-order per wave, no barrier needed
            const f32x4 al  = *(const f32x4*)&f_lds[w][g * 4];
            const f16x8 pf0 = *(const f16x8*)&P_lds[w][l16][g * 8];       // keys 0..31
            const f16x8 pf1 = *(const f16x8*)&P_lds[w][l16][32 + g * 8];  // keys 32..63
            __builtin_amdgcn_s_setprio(1);
#pragma unroll
            for (int jt = 0; jt < 4; ++jt) {
                const char* vr = (const char*)Vs + (jt * 16 + l16) * 128;
                const f16x8 vlo = *(const f16x8*)(vr + ((g * 16) ^ swl));
                const f16x8 vhi = *(const f16x8*)(vr + ((64 + g * 16) ^ swl));
#pragma unroll
                for (int r = 0; r < 4; ++r) cacc[jt][r] *= al[r];
                cacc[jt] = mfma16(pf0, vlo, cacc[jt]);
                cacc[jt] = mfma16(pf1, vhi, cacc[jt]);
            }
            __builtin_amdgcn_s_setprio(0);
            __syncthreads();   // protect Ks/Vs before next stage
        }

        if (g == 0) f_lds[w][l16] = 1.f / l_run;
        const f32x4 il = *(const f32x4*)&f_lds[w][g * 4];
#pragma unroll
        for (int jt = 0; jt < 4; ++jt)
#pragma unroll
            for (int r = 0; r < 4; ++r)
                ctx[((size_t)b * 2048 + qbase + g * 4 + r) * 1024 + h * 64 + jt * 16 + l16]
                    = (_Float16)(cacc[jt][r] * il[r]);
    }
}

// ---------------------------------------------------------------------------
// LayerNorm over rows of 1024 fp32; optional fp32 and f16 outputs.
// ---------------------------------------------------------------------------
__global__ __launch_bounds__(256) void ln_kernel(
    const float* __restrict__ in, const float* __restrict__ gam, const float* __restrict__ bet,
    float* __restrict__ out32, _Float16* __restrict__ out16)
{
    const int row = blockIdx.x, tid = threadIdx.x;
    const float4 x = ((const float4*)(in + (size_t)row * 1024))[tid];
    float s  = x.x + x.y + x.z + x.w;
    float s2 = x.x * x.x + x.y * x.y + x.z * x.z + x.w * x.w;
#pragma unroll
    for (int o = 32; o > 0; o >>= 1) {
        s  += __shfl_xor(s, o);
        s2 += __shfl_xor(s2, o);
    }
    __shared__ float red[8];
    if ((tid & 63) == 0) { red[tid >> 6] = s; red[4 + (tid >> 6)] = s2; }
    __syncthreads();
    const float S  = red[0] + red[1] + red[2] + red[3];
    const float S2 = red[4] + red[5] + red[6] + red[7];
    const float mu = S * (1.f / 1024.f);
    const float ir = rsqrtf(S2 * (1.f / 1024.f) - mu * mu + 1e-5f);
    const float4 gv = ((const float4*)gam)[tid];
    const float4 bv = ((const float4*)bet)[tid];
    float4 o;
    o.x = (x.x - mu) * ir * gv.x + bv.x;
    o.y = (x.y - mu) * ir * gv.y + bv.y;
    o.z = (x.z - mu) * ir * gv.z + bv.z;
    o.w = (x.w - mu) * ir * gv.w + bv.w;
    if (out32) ((float4*)(out32 + (size_t)row * 1024))[tid] = o;
    if (out16) {
        f16x4 h;
        h[0] = (_Float16)o.x; h[1] = (_Float16)o.y; h[2] = (_Float16)o.z; h[3] = (_Float16)o.w;
        *(f16x4*)(out16 + (size_t)row * 1024 + tid * 4) = h;
    }
}

// fp32 -> fp16 elementwise (float4 granularity)
__global__ __launch_bounds__(256) void cast_f16(const float* __restrict__ in,
                                                _Float16* __restrict__ out, int n4)
{
    const int i = blockIdx.x * 256 + threadIdx.x;
    if (i < n4) {
        const float4 v = ((const float4*)in)[i];
        f16x4 h;
        h[0] = (_Float16)v.x; h[1] = (_Float16)v.y; h[2] = (_Float16)v.z; h[3] = (_Float16)v.w;
        ((f16x4*)out)[i] = h;
    }
}

// dst[n][k] = (f16) src[k][n] — LDS-tiled transpose, K,N multiples of 64
__global__ __launch_bounds__(256) void transpose_cast(const float* __restrict__ src,
                                                      _Float16* __restrict__ dst, int K, int N)
{
    __shared__ float tile[64][65];
    const int n0 = blockIdx.x * 64, k0 = blockIdx.y * 64;
    const int tid = threadIdx.x;
#pragma unroll
    for (int it = 0; it < 16; ++it) {
        const int idx = it * 256 + tid;
        const int r = idx >> 6, c = idx & 63;
        tile[r][c] = src[(size_t)(k0 + r) * N + n0 + c];
    }
    __syncthreads();
#pragma unroll
    for (int it = 0; it < 16; ++it) {
        const int idx = it * 256 + tid;
        const int r = idx >> 6, c = idx & 63;
        dst[(size_t)(n0 + r) * K + k0 + c] = (_Float16)tile[c][r];
    }
}

// Wqkv_bt[n][d] = W{q|k|v}[h][d][kk]  (n = which*1024 + h*64 + kk)
__global__ __launch_bounds__(256) void pack_qkv_w(const float* __restrict__ Wq,
                                                  const float* __restrict__ Wk,
                                                  const float* __restrict__ Wv,
                                                  _Float16* __restrict__ dst)
{
    __shared__ float tile[64][65];
    const int n0 = blockIdx.x * 64, d0 = blockIdx.y * 64;
    const int which = n0 >> 10, hh = (n0 >> 6) & 15;
    const float* W = which == 0 ? Wq : (which == 1 ? Wk : Wv);
    const int tid = threadIdx.x;
#pragma unroll
    for (int it = 0; it < 16; ++it) {
        const int idx = it * 256 + tid;
        const int r = idx >> 6, c = idx & 63;      // r = d offset, c = kk
        tile[r][c] = W[((size_t)hh * 1024 + d0 + r) * 64 + c];
    }
    __syncthreads();
#pragma unroll
    for (int it = 0; it < 16; ++it) {
        const int idx = it * 256 + tid;
        const int r = idx >> 6, c = idx & 63;      // r = kk (n offset), c = d offset
        dst[(size_t)(n0 + r) * 1024 + d0 + c] = (_Float16)tile[c][r];
    }
}

extern "C" void kernel_launch(void* const* d_in, const int* in_sizes, int n_in,
                              void* d_out, int out_size, void* d_ws, size_t ws_size,
                              hipStream_t stream)
{
    const float* x    = (const float*)d_in[0];
    const float* Wq   = (const float*)d_in[1];
    const float* Wk   = (const float*)d_in[2];
    const float* Wv   = (const float*)d_in[3];
    const float* Wo   = (const float*)d_in[4];
    const float* ln1g = (const float*)d_in[5];
    const float* ln1b = (const float*)d_in[6];
    const float* W1   = (const float*)d_in[7];
    const float* b1   = (const float*)d_in[8];
    const float* W2   = (const float*)d_in[9];
    const float* b2   = (const float*)d_in[10];
    const float* ln2g = (const float*)d_in[11];
    const float* ln2b = (const float*)d_in[12];
    float* out = (float*)d_out;

    char* ws = (char*)d_ws;
    size_t off = 0;
    auto alloc = [&](size_t bytes) {
        void* p = ws + off;
        off += (bytes + 255) & ~(size_t)255;
        return p;
    };
    _Float16* x_h   = (_Float16*)alloc(8192ULL * 1024 * 2);
    _Float16* wqkv  = (_Float16*)alloc(3072ULL * 1024 * 2);
    _Float16* wo_t  = (_Float16*)alloc(1024ULL * 1024 * 2);
    _Float16* w1_t  = (_Float16*)alloc(4096ULL * 1024 * 2);
    _Float16* w2_t  = (_Float16*)alloc(1024ULL * 4096 * 2);
    _Float16* qbuf  = (_Float16*)alloc(8192ULL * 1024 * 2);  // region A: q,k,vT,ctx
    _Float16* kbuf  = (_Float16*)alloc(8192ULL * 1024 * 2);
    _Float16* vt    = (_Float16*)alloc(8192ULL * 1024 * 2);
    _Float16* ctx   = (_Float16*)alloc(8192ULL * 1024 * 2);
    _Float16* ff1   = qbuf;  // reuse region A (67.1 MB) after attention+Wo
    float*    resid = (float*)alloc(8192ULL * 1024 * 4);     // resid1, then resid2
    float*    h1f   = (float*)alloc(8192ULL * 1024 * 4);
    _Float16* h1h   = (_Float16*)alloc(8192ULL * 1024 * 2);
    if (off > ws_size) return;  // insufficient workspace -> fail loudly

    // weight/activation packing
    cast_f16<<<8192, 256, 0, stream>>>(x, x_h, 2097152);
    pack_qkv_w<<<dim3(48, 16), 256, 0, stream>>>(Wq, Wk, Wv, wqkv);
    transpose_cast<<<dim3(16, 16), 256, 0, stream>>>(Wo, wo_t, 1024, 1024);
    transpose_cast<<<dim3(64, 16), 256, 0, stream>>>(W1, w1_t, 1024, 4096);
    transpose_cast<<<dim3(16, 64), 256, 0, stream>>>(W2, w2_t, 4096, 1024);

    // QKV projection (fused, scattered epilogue)
    gemm_bt<0><<<dim3(64, 24), 256, 0, stream>>>(x_h, wqkv, 8192, 3072, 1024,
                                                 nullptr, nullptr, qbuf, kbuf, vt);
    // causal flash attention (block-cooperative KV staging, paired q-blocks)
    attn_kernel<<<dim3(16, 64), 256, 0, stream>>>(qbuf, kbuf, vt, ctx);
    // output projection + residual
    gemm_bt<1><<<dim3(64, 8), 256, 0, stream>>>(ctx, wo_t, 8192, 1024, 1024,
                                                x, nullptr, resid, nullptr, nullptr);
    ln_kernel<<<8192, 256, 0, stream>>>(resid, ln1g, ln1b, h1f, h1h);
    // FFN
    gemm_bt<2><<<dim3(64, 32), 256, 0, stream>>>(h1h, w1_t, 8192, 4096, 1024,
                                                 b1, nullptr, ff1, nullptr, nullptr);
    gemm_bt<3><<<dim3(64, 8), 256, 0, stream>>>(ff1, w2_t, 8192, 1024, 4096,
                                                b2, h1f, resid, nullptr, nullptr);
    ln_kernel<<<8192, 256, 0, stream>>>(resid, ln2g, ln2b, out, nullptr);
}